// Round 3
// baseline (268.713 us; speedup 1.0000x reference)
//
#include <hip/hip_runtime.h>
#include <hip/hip_bf16.h>
#include <cstdint>

typedef __bf16 bf16x8 __attribute__((ext_vector_type(8)));
typedef float f32x4 __attribute__((ext_vector_type(4)));

// ---------- helpers ----------
__device__ __forceinline__ unsigned short f2bf(float f) {
  union { float f; uint32_t u; } a; a.f = f;
  uint32_t r = a.u + 0x7fffu + ((a.u >> 16) & 1u);
  return (unsigned short)(r >> 16);
}
__device__ __forceinline__ void gload_lds16(const unsigned short* g, unsigned short* l) {
  __builtin_amdgcn_global_load_lds(
      (const __attribute__((address_space(1))) void*)g,
      (__attribute__((address_space(3))) void*)l, 16, 0, 0);
}

// ---------- merged cast kernel (unchanged from R2) ----------
__global__ void cast_all(const float* __restrict__ x, const float* __restrict__ W,
                         unsigned short* __restrict__ xb, unsigned short* __restrict__ Wt) {
  __shared__ float tileW[64][65];
  const int bx = blockIdx.x;
  const int t = threadIdx.x;
  if (bx < 4096) {
    size_t i = ((size_t)bx * 256 + t) * 8;
    float4 a = *(const float4*)(x + i);
    float4 b = *(const float4*)(x + i + 4);
    uint4 o;
    o.x = (uint32_t)f2bf(a.x) | ((uint32_t)f2bf(a.y) << 16);
    o.y = (uint32_t)f2bf(a.z) | ((uint32_t)f2bf(a.w) << 16);
    o.z = (uint32_t)f2bf(b.x) | ((uint32_t)f2bf(b.y) << 16);
    o.w = (uint32_t)f2bf(b.z) | ((uint32_t)f2bf(b.w) << 16);
    *(uint4*)(xb + i) = o;
  } else {
    const int b = bx - 4096;              // 0..767
    const int z = b >> 8;                 // 0..2
    const int rest = b & 255;
    const int bxx = rest & 15, byy = rest >> 4;
    const float* Wz = W + (size_t)z * 1048576;
    unsigned short* Wtz = Wt + (size_t)z * 1048576;
    const int x0 = bxx * 64, y0 = byy * 64;
    {
      const int r = t >> 4;               // 0..15
      const int c = (t & 15) * 4;
#pragma unroll
      for (int p = 0; p < 64; p += 16) {
        float4 v = *(const float4*)(Wz + (size_t)(y0 + p + r) * 1024 + x0 + c);
        tileW[p + r][c + 0] = v.x;
        tileW[p + r][c + 1] = v.y;
        tileW[p + r][c + 2] = v.z;
        tileW[p + r][c + 3] = v.w;
      }
    }
    __syncthreads();
    {
      const int dc = (t & 7) * 8;
#pragma unroll
      for (int p = 0; p < 64; p += 32) {
        const int e = p + (t >> 3);
        uint4 o;
        o.x = (uint32_t)f2bf(tileW[dc + 0][e]) | ((uint32_t)f2bf(tileW[dc + 1][e]) << 16);
        o.y = (uint32_t)f2bf(tileW[dc + 2][e]) | ((uint32_t)f2bf(tileW[dc + 3][e]) << 16);
        o.z = (uint32_t)f2bf(tileW[dc + 4][e]) | ((uint32_t)f2bf(tileW[dc + 5][e]) << 16);
        o.w = (uint32_t)f2bf(tileW[dc + 6][e]) | ((uint32_t)f2bf(tileW[dc + 7][e]) << 16);
        *(uint4*)(Wtz + (size_t)(x0 + e) * 1024 + y0 + dc) = o;
      }
    }
  }
}

// ---------- rowsum reduce: rowinv[r] = 1 / sum_j partial[j][r] ----------
__global__ void reduce_aux(const float* __restrict__ partial, float* __restrict__ rowinv) {
  const int r = blockIdx.x * 256 + threadIdx.x;   // 8192 rows
  float s = 0.f;
#pragma unroll
  for (int j = 0; j < 32; ++j) s += partial[(size_t)j * 8192 + r];
  rowinv[r] = 1.f / s;
}

// ---------- GEMM: C[m,n] = A[m,:] . Bt[n,:] ----------
// Tiles 128x128, BK=32. QUAD-buffered LDS (4 x 16KB = 64KB), prefetch
// distance 3 K-steps: stage(k+3) issued right after step k's barrier, so a
// load has ~3 compute phases (~1000-1800cy) to land -- covers L3/HBM miss
// latency on streamed B-panels (scores/PV). Counted s_waitcnt vmcnt(8)
// (never 0 in steady state) + raw s_barrier; NO __syncthreads (its vmcnt(0)
// drain is the documented ~20% stall). Single barrier per step: stage(k+3)
// overwrites buf[(k-1)&3], whose readers retired their ds_reads (lgkm waits
// precede their MFMAs) before reaching this barrier. Compiler fence after
// the barrier pins gload/ds_read program order across the raw s_barrier.
// XOR-swizzled LDS (verified conflict-free: SQ_LDS_BANK_CONFLICT 0).
// MODE 4 = merged QKV: z=0,1 -> bf16 C + z*sC; z=2 -> transposed Vt[b][e][s]
// MODE 5 = scores: epilogue exp(acc/32) -> bf16 P_un; per-row partial sums
// MODE 6 = PV: epilogue out = acc * rowinv (aux = precomputed 1/rowsum)
template <int MODE>
__global__ void __launch_bounds__(256)
gemm_bt(const unsigned short* __restrict__ Aall,
        const unsigned short* __restrict__ Btall,
        void* __restrict__ Call, unsigned short* __restrict__ VtPtr,
        float* __restrict__ aux,
        int K, int ldc, long sA, long sB, long sC, float scale) {
  __shared__ unsigned short As[4][4096];
  __shared__ unsigned short Bs[4][4096];
  const int t = threadIdx.x;
  const int lane = t & 63;
  const int quad = lane >> 4;
  const int l15 = lane & 15;
  const int wave = t >> 6;
  const int wm = (wave >> 1) * 64;
  const int wn = (wave & 1) * 64;
  const int z = blockIdx.z;

  const unsigned short* A = Aall + (size_t)z * sA + (size_t)blockIdx.x * 128 * K;
  const unsigned short* Bt = Btall + (size_t)z * sB + (size_t)blockIdx.y * 128 * K;

  const int srow = t >> 2;                             // 0..63
  const int scol = (((t & 3) ^ ((srow >> 1) & 3)) * 8);
  const unsigned short* ga = A + (size_t)srow * K + scol;
  const unsigned short* gb = Bt + (size_t)srow * K + scol;
  const size_t rowskip = (size_t)64 * K;

  const int aOff = (wm + l15) * 32 + (quad ^ ((l15 >> 1) & 3)) * 8;
  const int bOff = (wn + l15) * 32 + (quad ^ ((l15 >> 1) & 3)) * 8;

  f32x4 acc[4][4];
#pragma unroll
  for (int i = 0; i < 4; i++)
#pragma unroll
    for (int j = 0; j < 4; j++) acc[i][j] = (f32x4){0.f, 0.f, 0.f, 0.f};

  const int NT = K >> 5;   // K-steps of 32 (32 for K=1024, 64 for K=2048)

#define STAGE(S) do {                                            \
    const int kn_ = (S) * 32;                                    \
    const int bf_ = (S) & 3;                                     \
    gload_lds16(ga + kn_, &As[bf_][t * 8]);                      \
    gload_lds16(ga + rowskip + kn_, &As[bf_][2048 + t * 8]);     \
    gload_lds16(gb + kn_, &Bs[bf_][t * 8]);                      \
    gload_lds16(gb + rowskip + kn_, &Bs[bf_][2048 + t * 8]);     \
  } while (0)

  // prologue: stage steps 0,1,2 (12 loads in flight)
  STAGE(0);
  if (NT > 1) STAGE(1);
  if (NT > 2) STAGE(2);

  for (int k = 0; k < NT; ++k) {
    const int rem = NT - 1 - k;
    // complete step k's 4 loads; keep later steps' loads in flight.
    if (rem >= 2)      asm volatile("s_waitcnt vmcnt(8)" ::: "memory");
    else if (rem == 1) asm volatile("s_waitcnt vmcnt(4)" ::: "memory");
    else               asm volatile("s_waitcnt vmcnt(0)" ::: "memory");
    __builtin_amdgcn_s_barrier();
    asm volatile("" ::: "memory");       // pin: no gload/ds_read motion across barrier
    if (k + 3 < NT) STAGE(k + 3);

    const int buf = k & 3;
    const unsigned short* aB = &As[buf][aOff];
    const unsigned short* bB = &Bs[buf][bOff];
    bf16x8 a[4], b[4];
#pragma unroll
    for (int i = 0; i < 4; i++) a[i] = *(const bf16x8*)(aB + i * 512);
#pragma unroll
    for (int j = 0; j < 4; j++) b[j] = *(const bf16x8*)(bB + j * 512);
#pragma unroll
    for (int i = 0; i < 4; i++)
#pragma unroll
      for (int j = 0; j < 4; j++)
        acc[i][j] = __builtin_amdgcn_mfma_f32_16x16x32_bf16(a[i], b[j], acc[i][j], 0, 0, 0);
  }
#undef STAGE

  // C/D layout: col = lane&15, row = quad*4 + reg  [verified m89/m91]
  const int mbase = blockIdx.x * 128 + wm + quad * 4;
  const int nbase = blockIdx.y * 128 + wn + l15;

  if (MODE == 4) {
    if (z < 2) {
      unsigned short* C = (unsigned short*)Call + (size_t)z * sC;
#pragma unroll
      for (int mi = 0; mi < 4; mi++)
#pragma unroll
        for (int ni = 0; ni < 4; ni++) {
          const int m = mbase + mi * 16, n = nbase + ni * 16;
#pragma unroll
          for (int r = 0; r < 4; r++)
            C[(size_t)(m + r) * ldc + n] = f2bf(acc[mi][ni][r]);
        }
    } else {  // z==2: Vt[b][e=n][s] <- acc, m = b*2048 + s
      unsigned short* C = VtPtr;
#pragma unroll
      for (int mi = 0; mi < 4; mi++) {
        const int m = mbase + mi * 16;
        const int b = m >> 11, s = m & 2047;
#pragma unroll
        for (int ni = 0; ni < 4; ni++) {
          const int n = nbase + ni * 16;
          uint2 val;
          val.x = (uint32_t)f2bf(acc[mi][ni][0]) | ((uint32_t)f2bf(acc[mi][ni][1]) << 16);
          val.y = (uint32_t)f2bf(acc[mi][ni][2]) | ((uint32_t)f2bf(acc[mi][ni][3]) << 16);
          *(uint2*)(C + (size_t)b * 2097152 + (size_t)n * 2048 + s) = val;
        }
      }
    }
  } else if (MODE == 5) {
    // exp + store P_un + per-row partial sums
    unsigned short* C = (unsigned short*)Call + (size_t)z * sC;
    const int j = blockIdx.y * 2 + (wn >> 6);
#pragma unroll
    for (int mi = 0; mi < 4; mi++) {
#pragma unroll
      for (int r = 0; r < 4; r++) {
        const int m = mbase + mi * 16 + r;
        float s = 0.f;
#pragma unroll
        for (int ni = 0; ni < 4; ni++) {
          const float e = __expf(acc[mi][ni][r] * scale);
          C[(size_t)m * ldc + nbase + ni * 16] = f2bf(e);
          s += e;
        }
        s += __shfl_xor(s, 1);
        s += __shfl_xor(s, 2);
        s += __shfl_xor(s, 4);
        s += __shfl_xor(s, 8);
        if (l15 == 0) aux[(size_t)j * 8192 + (size_t)z * 2048 + m] = s;
      }
    }
  } else {  // MODE 6: PV, scale by precomputed 1/rowsum
    float* C = (float*)Call + (size_t)z * sC;
#pragma unroll
    for (int mi = 0; mi < 4; mi++) {
#pragma unroll
      for (int r = 0; r < 4; r++) {
        const int m = mbase + mi * 16 + r;
        const float inv = aux[(size_t)z * 2048 + m];   // broadcast across l15
#pragma unroll
        for (int ni = 0; ni < 4; ni++)
          C[(size_t)m * ldc + nbase + ni * 16] = acc[mi][ni][r] * inv;
      }
    }
  }
}

// ---------- launcher ----------
// B=4, S=2048, D=1024. Workspace (102 MB):
//   xb @0: 16MB | Wt @16MB: 6MB (dead after QKV; partial[32][8192] overlays
//   @16MB, rowinv[8192] @18MB) | Q @22MB | K @38MB | Vt @54MB [4][e][s]
//   Sb @70MB: 32MB P_unnorm bf16 [4][2048][2048]
extern "C" void kernel_launch(void* const* d_in, const int* in_sizes, int n_in,
                              void* d_out, int out_size, void* d_ws, size_t ws_size,
                              hipStream_t stream) {
  const float* x = (const float*)d_in[0];
  const float* W = (const float*)d_in[1];
  float* out = (float*)d_out;
  char* ws = (char*)d_ws;
  unsigned short* xb = (unsigned short*)(ws);
  unsigned short* Wt = (unsigned short*)(ws + (16ll << 20));
  float* partial     = (float*)(ws + (16ll << 20));   // overlays Wt after QKV
  float* rowinv      = (float*)(ws + (18ll << 20));   // overlays Wt after QKV
  unsigned short* Q  = (unsigned short*)(ws + (22ll << 20));
  unsigned short* Kb = (unsigned short*)(ws + (38ll << 20));
  unsigned short* Vt = (unsigned short*)(ws + (54ll << 20));
  unsigned short* Sb = (unsigned short*)(ws + (70ll << 20));

  cast_all<<<4864, 256, 0, stream>>>(x, W, xb, Wt);

  // merged QKV projection: z=0 -> Q, z=1 -> K, z=2 -> Vt (transposed store)
  gemm_bt<4><<<dim3(64, 8, 3), 256, 0, stream>>>(
      xb, Wt, Q, Vt, nullptr, 1024, 1024, 0L, 1048576L, 8388608L, 1.0f);
  // P_un = exp(Q K^T / 32), bf16, + per-row partial sums into `partial`
  gemm_bt<5><<<dim3(16, 16, 4), 256, 0, stream>>>(
      Q, Kb, Sb, nullptr, partial, 1024, 2048, 2097152L, 2097152L, 4194304L, 0.03125f);
  // rowinv = 1 / rowsum
  reduce_aux<<<32, 256, 0, stream>>>(partial, rowinv);
  // out = (P_un @ V) * rowinv  (fp32 store to d_out)
  gemm_bt<6><<<dim3(16, 8, 4), 256, 0, stream>>>(
      Sb, Vt, out, nullptr, rowinv, 2048, 1024, 4194304L, 2097152L, 2097152L, 1.0f);
}

// Round 4
// 241.947 us; speedup vs baseline: 1.1106x; 1.1106x over previous
//
#include <hip/hip_runtime.h>
#include <hip/hip_bf16.h>
#include <cstdint>

typedef __bf16 bf16x8 __attribute__((ext_vector_type(8)));
typedef float f32x4 __attribute__((ext_vector_type(4)));

// ---------- helpers ----------
__device__ __forceinline__ unsigned short f2bf(float f) {
  union { float f; uint32_t u; } a; a.f = f;
  uint32_t r = a.u + 0x7fffu + ((a.u >> 16) & 1u);
  return (unsigned short)(r >> 16);
}
__device__ __forceinline__ void gload_lds16(const unsigned short* g, unsigned short* l) {
  __builtin_amdgcn_global_load_lds(
      (const __attribute__((address_space(1))) void*)g,
      (__attribute__((address_space(3))) void*)l, 16, 0, 0);
}

// ---------- merged cast kernel (R2, unchanged) ----------
__global__ void cast_all(const float* __restrict__ x, const float* __restrict__ W,
                         unsigned short* __restrict__ xb, unsigned short* __restrict__ Wt) {
  __shared__ float tileW[64][65];
  const int bx = blockIdx.x;
  const int t = threadIdx.x;
  if (bx < 4096) {
    size_t i = ((size_t)bx * 256 + t) * 8;
    float4 a = *(const float4*)(x + i);
    float4 b = *(const float4*)(x + i + 4);
    uint4 o;
    o.x = (uint32_t)f2bf(a.x) | ((uint32_t)f2bf(a.y) << 16);
    o.y = (uint32_t)f2bf(a.z) | ((uint32_t)f2bf(a.w) << 16);
    o.z = (uint32_t)f2bf(b.x) | ((uint32_t)f2bf(b.y) << 16);
    o.w = (uint32_t)f2bf(b.z) | ((uint32_t)f2bf(b.w) << 16);
    *(uint4*)(xb + i) = o;
  } else {
    const int b = bx - 4096;              // 0..767
    const int z = b >> 8;                 // 0..2
    const int rest = b & 255;
    const int bxx = rest & 15, byy = rest >> 4;
    const float* Wz = W + (size_t)z * 1048576;
    unsigned short* Wtz = Wt + (size_t)z * 1048576;
    const int x0 = bxx * 64, y0 = byy * 64;
    {
      const int r = t >> 4;               // 0..15
      const int c = (t & 15) * 4;
#pragma unroll
      for (int p = 0; p < 64; p += 16) {
        float4 v = *(const float4*)(Wz + (size_t)(y0 + p + r) * 1024 + x0 + c);
        tileW[p + r][c + 0] = v.x;
        tileW[p + r][c + 1] = v.y;
        tileW[p + r][c + 2] = v.z;
        tileW[p + r][c + 3] = v.w;
      }
    }
    __syncthreads();
    {
      const int dc = (t & 7) * 8;
#pragma unroll
      for (int p = 0; p < 64; p += 32) {
        const int e = p + (t >> 3);
        uint4 o;
        o.x = (uint32_t)f2bf(tileW[dc + 0][e]) | ((uint32_t)f2bf(tileW[dc + 1][e]) << 16);
        o.y = (uint32_t)f2bf(tileW[dc + 2][e]) | ((uint32_t)f2bf(tileW[dc + 3][e]) << 16);
        o.z = (uint32_t)f2bf(tileW[dc + 4][e]) | ((uint32_t)f2bf(tileW[dc + 5][e]) << 16);
        o.w = (uint32_t)f2bf(tileW[dc + 6][e]) | ((uint32_t)f2bf(tileW[dc + 7][e]) << 16);
        *(uint4*)(Wtz + (size_t)(x0 + e) * 1024 + y0 + dc) = o;
      }
    }
  }
}

// ---------- rowsum reduce: rowinv[r] = 1 / sum_j partial[j][r] ----------
__global__ void reduce_aux(const float* __restrict__ partial, float* __restrict__ rowinv) {
  const int r = blockIdx.x * 256 + threadIdx.x;   // 8192 rows
  float s = 0.f;
#pragma unroll
  for (int j = 0; j < 32; ++j) s += partial[(size_t)j * 8192 + r];
  rowinv[r] = 1.f / s;
}

// ---------- 2-phase GEMM (R2-proven): QKV + PV ----------
// Tiles 128x128, BK=32, double-buffered LDS, __syncthreads per K-step,
// XOR-swizzled (SQ_LDS_BANK_CONFLICT verified 0).
// MODE 4 = merged QKV: z=0,1 -> bf16 C + z*sC; z=2 -> transposed Vt[b][e][s]
// MODE 6 = PV: epilogue out = acc * rowinv (aux = precomputed 1/rowsum)
template <int MODE>
__global__ void __launch_bounds__(256)
gemm_bt(const unsigned short* __restrict__ Aall,
        const unsigned short* __restrict__ Btall,
        void* __restrict__ Call, unsigned short* __restrict__ VtPtr,
        float* __restrict__ aux,
        int K, int ldc, long sA, long sB, long sC) {
  __shared__ unsigned short As[2][4096];
  __shared__ unsigned short Bs[2][4096];
  const int t = threadIdx.x;
  const int lane = t & 63;
  const int quad = lane >> 4;
  const int l15 = lane & 15;
  const int wave = t >> 6;
  const int wm = (wave >> 1) * 64;
  const int wn = (wave & 1) * 64;
  const int z = blockIdx.z;

  const unsigned short* A = Aall + (size_t)z * sA + (size_t)blockIdx.x * 128 * K;
  const unsigned short* Bt = Btall + (size_t)z * sB + (size_t)blockIdx.y * 128 * K;

  const int srow = t >> 2;                             // 0..63
  const int scol = (((t & 3) ^ ((srow >> 1) & 3)) * 8);
  const unsigned short* ga = A + (size_t)srow * K + scol;
  const unsigned short* gb = Bt + (size_t)srow * K + scol;
  const size_t rowskip = (size_t)64 * K;

  const int aOff = (wm + l15) * 32 + (quad ^ ((l15 >> 1) & 3)) * 8;
  const int bOff = (wn + l15) * 32 + (quad ^ ((l15 >> 1) & 3)) * 8;

  f32x4 acc[4][4];
#pragma unroll
  for (int i = 0; i < 4; i++)
#pragma unroll
    for (int j = 0; j < 4; j++) acc[i][j] = (f32x4){0.f, 0.f, 0.f, 0.f};

  gload_lds16(ga, &As[0][t * 8]);
  gload_lds16(ga + rowskip, &As[0][2048 + t * 8]);
  gload_lds16(gb, &Bs[0][t * 8]);
  gload_lds16(gb + rowskip, &Bs[0][2048 + t * 8]);

  int buf = 0;
  for (int k0 = 0; k0 < K; k0 += 32, buf ^= 1) {
    __syncthreads();
    if (k0 + 32 < K) {
      const int kn = k0 + 32;
      gload_lds16(ga + kn, &As[buf ^ 1][t * 8]);
      gload_lds16(ga + rowskip + kn, &As[buf ^ 1][2048 + t * 8]);
      gload_lds16(gb + kn, &Bs[buf ^ 1][t * 8]);
      gload_lds16(gb + rowskip + kn, &Bs[buf ^ 1][2048 + t * 8]);
    }
    const unsigned short* aB = &As[buf][aOff];
    const unsigned short* bB = &Bs[buf][bOff];
    bf16x8 a[4], b[4];
#pragma unroll
    for (int i = 0; i < 4; i++) a[i] = *(const bf16x8*)(aB + i * 512);
#pragma unroll
    for (int j = 0; j < 4; j++) b[j] = *(const bf16x8*)(bB + j * 512);
#pragma unroll
    for (int i = 0; i < 4; i++)
#pragma unroll
      for (int j = 0; j < 4; j++)
        acc[i][j] = __builtin_amdgcn_mfma_f32_16x16x32_bf16(a[i], b[j], acc[i][j], 0, 0, 0);
  }

  // C/D layout: col = lane&15, row = quad*4 + reg  [verified m89/m91]
  const int mbase = blockIdx.x * 128 + wm + quad * 4;
  const int nbase = blockIdx.y * 128 + wn + l15;

  if (MODE == 4) {
    if (z < 2) {
      unsigned short* C = (unsigned short*)Call + (size_t)z * sC;
#pragma unroll
      for (int mi = 0; mi < 4; mi++)
#pragma unroll
        for (int ni = 0; ni < 4; ni++) {
          const int m = mbase + mi * 16, n = nbase + ni * 16;
#pragma unroll
          for (int r = 0; r < 4; r++)
            C[(size_t)(m + r) * ldc + n] = f2bf(acc[mi][ni][r]);
        }
    } else {  // z==2: Vt[b][e=n][s] <- acc, m = b*2048 + s
      unsigned short* C = VtPtr;
#pragma unroll
      for (int mi = 0; mi < 4; mi++) {
        const int m = mbase + mi * 16;
        const int b = m >> 11, s = m & 2047;
#pragma unroll
        for (int ni = 0; ni < 4; ni++) {
          const int n = nbase + ni * 16;
          uint2 val;
          val.x = (uint32_t)f2bf(acc[mi][ni][0]) | ((uint32_t)f2bf(acc[mi][ni][1]) << 16);
          val.y = (uint32_t)f2bf(acc[mi][ni][2]) | ((uint32_t)f2bf(acc[mi][ni][3]) << 16);
          *(uint2*)(C + (size_t)b * 2097152 + (size_t)n * 2048 + s) = val;
        }
      }
    }
  } else {  // MODE 6: PV, scale by precomputed 1/rowsum
    float* C = (float*)Call + (size_t)z * sC;
#pragma unroll
    for (int mi = 0; mi < 4; mi++) {
#pragma unroll
      for (int r = 0; r < 4; r++) {
        const int m = mbase + mi * 16 + r;
        const float inv = aux[(size_t)z * 2048 + m];   // broadcast across l15
#pragma unroll
        for (int ni = 0; ni < 4; ni++)
          C[(size_t)m * ldc + nbase + ni * 16] = acc[mi][ni][r] * inv;
      }
    }
  }
}

// ---------- 8-phase 256x256 GEMM: SCORES ONLY ----------
// Grid (8,8,4)=256 blocks = exactly 1/CU (no tail). 512 thr, 8 waves (2Mx4N),
// per-wave 128x64, acc[8][4]. BK=64 as two k-halves. LDS 128KB.
// Phase = {ds_read subtile; STAGE 1 region; sched_barrier; s_barrier;
//          lgkmcnt(0); sched_barrier; setprio(1); 16 MFMA; setprio(0);
//          sched_barrier; s_barrier}. Counted vmcnt(6) ONLY at tile
// boundaries (completes exactly the incoming tile; 3 regions in flight).
// Rotation (race-audited, numerics verified in R1): at tile kt issue
// A(kt+1,kh1)@P1, B(kt+2,kh0)@P2, A(kt+2,kh0)@P3, B(kt+2,kh1)@P4.
// Epilogue: exp(acc/32) -> bf16 P_un + per-row partial sums (j=by*4+wn).
__global__ void __launch_bounds__(512, 2)
gemm8_scores(const unsigned short* __restrict__ Aall,
             const unsigned short* __restrict__ Btall,
             unsigned short* __restrict__ Call, float* __restrict__ aux,
             int K, int ldc, long sA, long sB, long sC, float scale) {
  __shared__ unsigned short As[2][2][8192];  // [dbuf][khalf][256 rows x 32]
  __shared__ unsigned short Bs[2][2][8192];
  const int t = threadIdx.x;
  const int lane = t & 63;
  const int quad = lane >> 4;
  const int l15 = lane & 15;
  const int wave = t >> 6;
  const int wm = wave >> 2;   // 0..1 : rows wm*128..+127
  const int wn = wave & 3;    // 0..3 : cols wn*64..+63
  const int z = blockIdx.z;
  const int NT = K >> 6;      // 16 for K=1024

  const unsigned short* Ab = Aall + (size_t)z * sA + (size_t)blockIdx.x * 256 * K;
  const unsigned short* Bb = Btall + (size_t)z * sB + (size_t)blockIdx.y * 256 * K;

  const int sc = (((t & 3) ^ ((t >> 3) & 3)) * 8);
  const unsigned short* gA = Ab + (size_t)(t >> 2) * K + sc;
  const unsigned short* gB = Bb + (size_t)(t >> 2) * K + sc;
  const size_t half2 = (size_t)128 * K;

  const int swz = (quad ^ ((l15 >> 1) & 3)) * 8;
  const int aRd = (wm * 128 + l15) * 32 + swz;
  const int bRd = (wn * 64 + l15) * 32 + swz;

  f32x4 acc[8][4];
#pragma unroll
  for (int i = 0; i < 8; ++i)
#pragma unroll
    for (int j = 0; j < 4; ++j) acc[i][j] = (f32x4){0.f, 0.f, 0.f, 0.f};

#define STG_A(TT, KH) do { \
    const unsigned short* g_ = gA + (TT) * 64 + (KH) * 32; \
    unsigned short* d_ = &As[(TT) & 1][KH][t * 8]; \
    gload_lds16(g_, d_); \
    gload_lds16(g_ + half2, d_ + 4096); \
  } while (0)
#define STG_B(TT, KH) do { \
    const unsigned short* g_ = gB + (TT) * 64 + (KH) * 32; \
    unsigned short* d_ = &Bs[(TT) & 1][KH][t * 8]; \
    gload_lds16(g_, d_); \
    gload_lds16(g_ + half2, d_ + 4096); \
  } while (0)
#define PHASE_OPEN() do { \
    __builtin_amdgcn_sched_barrier(0); \
    __builtin_amdgcn_s_barrier(); \
    asm volatile("s_waitcnt lgkmcnt(0)" ::: "memory"); \
    __builtin_amdgcn_sched_barrier(0); \
    __builtin_amdgcn_s_setprio(1); \
  } while (0)
#define PHASE_CLOSE() do { \
    __builtin_amdgcn_s_setprio(0); \
    __builtin_amdgcn_sched_barrier(0); \
    __builtin_amdgcn_s_barrier(); \
  } while (0)

  // prologue: tile0 all four regions, tile1 first three; complete tile0.
  STG_B(0, 0); STG_A(0, 0); STG_B(0, 1); STG_A(0, 1);
  STG_B(1, 0); STG_A(1, 0); STG_B(1, 1);
  asm volatile("s_waitcnt vmcnt(6)" ::: "memory");
  __builtin_amdgcn_s_barrier();

  for (int kt = 0; kt < NT; ++kt) {
    const int buf = kt & 1;
    bf16x8 bb[4], a[4];

    // ---- P1: khalf=0, wave-row-half 0 ----
#pragma unroll
    for (int j = 0; j < 4; ++j) bb[j] = *(const bf16x8*)&Bs[buf][0][bRd + j * 512];
#pragma unroll
    for (int i = 0; i < 4; ++i) a[i] = *(const bf16x8*)&As[buf][0][aRd + i * 512];
    if (kt + 1 < NT) STG_A(kt + 1, 1);
    PHASE_OPEN();
#pragma unroll
    for (int i = 0; i < 4; ++i)
#pragma unroll
      for (int j = 0; j < 4; ++j)
        acc[i][j] = __builtin_amdgcn_mfma_f32_16x16x32_bf16(a[i], bb[j], acc[i][j], 0, 0, 0);
    PHASE_CLOSE();

    // ---- P2: khalf=0, wave-row-half 1 (reuse bb) ----
#pragma unroll
    for (int i = 0; i < 4; ++i) a[i] = *(const bf16x8*)&As[buf][0][aRd + 2048 + i * 512];
    if (kt + 2 < NT) STG_B(kt + 2, 0);
    PHASE_OPEN();
#pragma unroll
    for (int i = 0; i < 4; ++i)
#pragma unroll
      for (int j = 0; j < 4; ++j)
        acc[4 + i][j] = __builtin_amdgcn_mfma_f32_16x16x32_bf16(a[i], bb[j], acc[4 + i][j], 0, 0, 0);
    PHASE_CLOSE();

    // ---- P3: khalf=1, wave-row-half 0 ----
#pragma unroll
    for (int j = 0; j < 4; ++j) bb[j] = *(const bf16x8*)&Bs[buf][1][bRd + j * 512];
#pragma unroll
    for (int i = 0; i < 4; ++i) a[i] = *(const bf16x8*)&As[buf][1][aRd + i * 512];
    if (kt + 2 < NT) STG_A(kt + 2, 0);
    PHASE_OPEN();
#pragma unroll
    for (int i = 0; i < 4; ++i)
#pragma unroll
      for (int j = 0; j < 4; ++j)
        acc[i][j] = __builtin_amdgcn_mfma_f32_16x16x32_bf16(a[i], bb[j], acc[i][j], 0, 0, 0);
    PHASE_CLOSE();

    // ---- P4: khalf=1, wave-row-half 1 (reuse bb) ----
#pragma unroll
    for (int i = 0; i < 4; ++i) a[i] = *(const bf16x8*)&As[buf][1][aRd + 2048 + i * 512];
    if (kt + 2 < NT) STG_B(kt + 2, 1);
    __builtin_amdgcn_sched_barrier(0);
    __builtin_amdgcn_s_barrier();
    asm volatile("s_waitcnt lgkmcnt(0)" ::: "memory");
    __builtin_amdgcn_sched_barrier(0);
    __builtin_amdgcn_s_setprio(1);
#pragma unroll
    for (int i = 0; i < 4; ++i)
#pragma unroll
      for (int j = 0; j < 4; ++j)
        acc[4 + i][j] = __builtin_amdgcn_mfma_f32_16x16x32_bf16(a[i], bb[j], acc[4 + i][j], 0, 0, 0);
    __builtin_amdgcn_s_setprio(0);
    __builtin_amdgcn_sched_barrier(0);
    // tile boundary: complete the incoming tile; keep 3 regions in flight.
    if (kt < NT - 2) {
      asm volatile("s_waitcnt vmcnt(6)" ::: "memory");
    } else if (kt == NT - 2) {
      asm volatile("s_waitcnt vmcnt(0)" ::: "memory");
    }
    __builtin_amdgcn_s_barrier();
  }
#undef STG_A
#undef STG_B
#undef PHASE_OPEN
#undef PHASE_CLOSE

  // epilogue: exp + store P_un + per-row partial sums
  const int mb = blockIdx.x * 256 + wm * 128 + quad * 4;
  const int nb = blockIdx.y * 256 + wn * 64 + l15;
  const int j = blockIdx.y * 4 + wn;   // 0..31
#pragma unroll
  for (int mi = 0; mi < 8; ++mi) {
#pragma unroll
    for (int r = 0; r < 4; ++r) {
      const int m = mb + mi * 16 + r;
      float s = 0.f;
#pragma unroll
      for (int ni = 0; ni < 4; ++ni) {
        const float e = __expf(acc[mi][ni][r] * scale);
        Call[(size_t)z * sC + (size_t)m * ldc + nb + ni * 16] = f2bf(e);
        s += e;
      }
      s += __shfl_xor(s, 1);
      s += __shfl_xor(s, 2);
      s += __shfl_xor(s, 4);
      s += __shfl_xor(s, 8);
      if (l15 == 0) aux[(size_t)j * 8192 + (size_t)z * 2048 + m] = s;
    }
  }
}

// ---------- launcher ----------
// B=4, S=2048, D=1024. Workspace (102 MB):
//   xb @0: 16MB | Wt @16MB: 6MB (dead after QKV; partial[32][8192] overlays
//   @16MB, rowinv[8192] @18MB) | Q @22MB | K @38MB | Vt @54MB [4][e][s]
//   Sb @70MB: 32MB P_unnorm bf16 [4][2048][2048]
extern "C" void kernel_launch(void* const* d_in, const int* in_sizes, int n_in,
                              void* d_out, int out_size, void* d_ws, size_t ws_size,
                              hipStream_t stream) {
  const float* x = (const float*)d_in[0];
  const float* W = (const float*)d_in[1];
  float* out = (float*)d_out;
  char* ws = (char*)d_ws;
  unsigned short* xb = (unsigned short*)(ws);
  unsigned short* Wt = (unsigned short*)(ws + (16ll << 20));
  float* partial     = (float*)(ws + (16ll << 20));   // overlays Wt after QKV
  float* rowinv      = (float*)(ws + (18ll << 20));   // overlays Wt after QKV
  unsigned short* Q  = (unsigned short*)(ws + (22ll << 20));
  unsigned short* Kb = (unsigned short*)(ws + (38ll << 20));
  unsigned short* Vt = (unsigned short*)(ws + (54ll << 20));
  unsigned short* Sb = (unsigned short*)(ws + (70ll << 20));

  cast_all<<<4864, 256, 0, stream>>>(x, W, xb, Wt);

  // merged QKV projection (2-phase): z=0 -> Q, z=1 -> K, z=2 -> Vt
  gemm_bt<4><<<dim3(64, 8, 3), 256, 0, stream>>>(
      xb, Wt, Q, Vt, nullptr, 1024, 1024, 0L, 1048576L, 8388608L);
  // P_un = exp(Q K^T / 32) (8-phase 256², grid exactly 256 blocks)
  gemm8_scores<<<dim3(8, 8, 4), 512, 0, stream>>>(
      Q, Kb, Sb, partial, 1024, 2048, 2097152L, 2097152L, 4194304L, 0.03125f);
  // rowinv = 1 / rowsum
  reduce_aux<<<32, 256, 0, stream>>>(partial, rowinv);
  // out = (P_un @ V) * rowinv  (2-phase, fp32 store to d_out)
  gemm_bt<6><<<dim3(16, 8, 4), 256, 0, stream>>>(
      Sb, Vt, out, nullptr, rowinv, 2048, 1024, 4194304L, 2097152L, 2097152L);
}